// Round 1
// baseline (763.100 us; speedup 1.0000x reference)
//
#include <hip/hip_runtime.h>

// GraphSAGE 2-layer inference, fp32, MI355X.
// Sizes (fixed by the problem):
#define NUM_NODES 1000000
#define HDIM      128
#define OUT_DIM   64
#define FANOUT    16
#define N_SRC0    1048576
#define N_DST0    65536
#define N_DST1    4096

#define THREADS   256
#define MTILE     64      // nodes per block

// ---------------- K0: weight prep ----------------
// Wcat[k][c] (k<128 -> W_self[c][k], k>=128 -> W_neigh[c][k-128]), row-major [256][128].
// WoutT[c][o] = W_out[o][c], row-major [128][64].
// bias[c] = b_self[c] + b_neigh[c].
__global__ __launch_bounds__(THREADS) void prep_kernel(
    const float* __restrict__ Ws0, const float* __restrict__ Wn0,
    const float* __restrict__ Ws1, const float* __restrict__ Wn1,
    const float* __restrict__ Wout,
    const float* __restrict__ bs0, const float* __restrict__ bn0,
    const float* __restrict__ bs1, const float* __restrict__ bn1,
    float* __restrict__ Wcat0, float* __restrict__ Wcat1,
    float* __restrict__ WoutT, float* __restrict__ bias0, float* __restrict__ bias1) {
  int tid = blockIdx.x * blockDim.x + threadIdx.x;
  int stride = gridDim.x * blockDim.x;
  for (int i = tid; i < 256 * 128; i += stride) {
    int k = i >> 7, c = i & 127;
    Wcat0[i] = (k < 128) ? Ws0[c * 128 + k] : Wn0[c * 128 + (k - 128)];
    Wcat1[i] = (k < 128) ? Ws1[c * 128 + k] : Wn1[c * 128 + (k - 128)];
  }
  for (int i = tid; i < 128 * 64; i += stride) {
    int c = i >> 6, o = i & 63;
    WoutT[i] = Wout[o * 128 + c];
  }
  for (int i = tid; i < 128; i += stride) {
    bias0[i] = bs0[i] + bn0[i];
    bias1[i] = bs1[i] + bn1[i];
  }
}

// ---------------- K1: layer 0 (gather from emb via input_nodes, GEMM, ReLU) ----------------
__global__ __launch_bounds__(THREADS) void layer0_kernel(
    const float* __restrict__ emb, const int* __restrict__ input_nodes,
    const int* __restrict__ nbr0, const float* __restrict__ Wcat0,
    const float* __restrict__ bias0, float* __restrict__ H0) {
  __shared__ float Xs[MTILE][256];   // 64 KB: [node][k]  k<128 self, k>=128 neigh-mean
  const int tid = threadIdx.x;
  const int node0 = blockIdx.x * MTILE;
  const int ln = tid >> 5;   // 0..7
  const int ch = tid & 31;   // float4 chunk within a 128-float row
  const float4* __restrict__ emb4 = (const float4*)emb;

  // ---- gather phase: each thread owns (8 nodes) x (one float4 chunk) ----
  for (int g = 0; g < 8; ++g) {
    const int nl = g * 8 + ln;          // local node 0..63
    const int n  = node0 + nl;          // global dst node
    const int self = input_nodes[n];
    float4 s = emb4[(size_t)self * 32 + ch];
    float4 acc; acc.x = 0.f; acc.y = 0.f; acc.z = 0.f; acc.w = 0.f;
#pragma unroll
    for (int j = 0; j < FANOUT; ++j) {
      const int nb  = nbr0[n * FANOUT + j];
      const int src = input_nodes[nb];
      float4 v = emb4[(size_t)src * 32 + ch];
      acc.x += v.x; acc.y += v.y; acc.z += v.z; acc.w += v.w;
    }
    const float inv = 1.0f / (float)FANOUT;
    float4 m; m.x = acc.x * inv; m.y = acc.y * inv; m.z = acc.z * inv; m.w = acc.w * inv;
    *(float4*)&Xs[nl][ch * 4] = s;
    *(float4*)&Xs[nl][128 + ch * 4] = m;
  }
  __syncthreads();

  // ---- GEMM phase: C[64][128] = Xs[64][256] @ Wcat0[256][128] + bias, ReLU ----
  const int ct = tid & 31;   // cols ct*4 .. ct*4+3
  const int nt = tid >> 5;   // nodes nt*8 .. nt*8+7
  float acc[8][4];
  {
    float4 b = *(const float4*)&bias0[ct * 4];
#pragma unroll
    for (int i = 0; i < 8; ++i) { acc[i][0] = b.x; acc[i][1] = b.y; acc[i][2] = b.z; acc[i][3] = b.w; }
  }
  const float4* __restrict__ W4 = (const float4*)Wcat0;
  for (int k = 0; k < 256; k += 4) {
    float4 wv[4];
#pragma unroll
    for (int d = 0; d < 4; ++d) wv[d] = W4[(size_t)(k + d) * 32 + ct];
#pragma unroll
    for (int i = 0; i < 8; ++i) {
      float4 x = *(const float4*)&Xs[nt * 8 + i][k];
      float xs[4] = {x.x, x.y, x.z, x.w};
#pragma unroll
      for (int d = 0; d < 4; ++d) {
        acc[i][0] = fmaf(xs[d], wv[d].x, acc[i][0]);
        acc[i][1] = fmaf(xs[d], wv[d].y, acc[i][1]);
        acc[i][2] = fmaf(xs[d], wv[d].z, acc[i][2]);
        acc[i][3] = fmaf(xs[d], wv[d].w, acc[i][3]);
      }
    }
  }
#pragma unroll
  for (int i = 0; i < 8; ++i) {
    float4 o;
    o.x = fmaxf(acc[i][0], 0.f); o.y = fmaxf(acc[i][1], 0.f);
    o.z = fmaxf(acc[i][2], 0.f); o.w = fmaxf(acc[i][3], 0.f);
    *(float4*)&H0[(size_t)(node0 + nt * 8 + i) * HDIM + ct * 4] = o;
  }
}

// ---------------- K2: layer 1 (gather from H0) + fused output projection ----------------
__global__ __launch_bounds__(THREADS) void layer1_kernel(
    const float* __restrict__ H0, const int* __restrict__ nbr1,
    const float* __restrict__ Wcat1, const float* __restrict__ bias1,
    const float* __restrict__ WoutT, const float* __restrict__ b_out,
    float* __restrict__ out) {
  __shared__ float Xs[MTILE][256];
  const int tid = threadIdx.x;
  const int node0 = blockIdx.x * MTILE;
  const int ln = tid >> 5;
  const int ch = tid & 31;
  const float4* __restrict__ H04 = (const float4*)H0;

  for (int g = 0; g < 8; ++g) {
    const int nl = g * 8 + ln;
    const int n  = node0 + nl;
    float4 s = H04[(size_t)n * 32 + ch];
    float4 acc; acc.x = 0.f; acc.y = 0.f; acc.z = 0.f; acc.w = 0.f;
#pragma unroll
    for (int j = 0; j < FANOUT; ++j) {
      const int src = nbr1[n * FANOUT + j];
      float4 v = H04[(size_t)src * 32 + ch];
      acc.x += v.x; acc.y += v.y; acc.z += v.z; acc.w += v.w;
    }
    const float inv = 1.0f / (float)FANOUT;
    float4 m; m.x = acc.x * inv; m.y = acc.y * inv; m.z = acc.z * inv; m.w = acc.w * inv;
    *(float4*)&Xs[nl][ch * 4] = s;
    *(float4*)&Xs[nl][128 + ch * 4] = m;
  }
  __syncthreads();

  const int ct = tid & 31;
  const int nt = tid >> 5;
  float acc[8][4];
  {
    float4 b = *(const float4*)&bias1[ct * 4];
#pragma unroll
    for (int i = 0; i < 8; ++i) { acc[i][0] = b.x; acc[i][1] = b.y; acc[i][2] = b.z; acc[i][3] = b.w; }
  }
  const float4* __restrict__ W4 = (const float4*)Wcat1;
  for (int k = 0; k < 256; k += 4) {
    float4 wv[4];
#pragma unroll
    for (int d = 0; d < 4; ++d) wv[d] = W4[(size_t)(k + d) * 32 + ct];
#pragma unroll
    for (int i = 0; i < 8; ++i) {
      float4 x = *(const float4*)&Xs[nt * 8 + i][k];
      float xs[4] = {x.x, x.y, x.z, x.w};
#pragma unroll
      for (int d = 0; d < 4; ++d) {
        acc[i][0] = fmaf(xs[d], wv[d].x, acc[i][0]);
        acc[i][1] = fmaf(xs[d], wv[d].y, acc[i][1]);
        acc[i][2] = fmaf(xs[d], wv[d].z, acc[i][2]);
        acc[i][3] = fmaf(xs[d], wv[d].w, acc[i][3]);
      }
    }
  }
  __syncthreads();  // done reading Xs; reuse it for C1 (no ReLU on layer-1 output)

  float (*C1)[HDIM] = (float(*)[HDIM])Xs;   // [64][128], 32 KB alias
#pragma unroll
  for (int i = 0; i < 8; ++i) {
    float4 o; o.x = acc[i][0]; o.y = acc[i][1]; o.z = acc[i][2]; o.w = acc[i][3];
    *(float4*)&C1[nt * 8 + i][ct * 4] = o;
  }
  __syncthreads();

  // out[64 nodes][64 cols] = C1[64][128] @ WoutT[128][64] + b_out
  // thread: 8 nodes (nt) x 2 cols (ct -> cols ct*2, ct*2+1)
  float facc[8][2];
  {
    float2 b = *(const float2*)&b_out[ct * 2];
#pragma unroll
    for (int i = 0; i < 8; ++i) { facc[i][0] = b.x; facc[i][1] = b.y; }
  }
  const float2* __restrict__ Wo2 = (const float2*)WoutT;
  for (int c = 0; c < 128; ++c) {
    float2 w = Wo2[(size_t)c * 32 + ct];
#pragma unroll
    for (int i = 0; i < 8; ++i) {
      float x = C1[nt * 8 + i][c];
      facc[i][0] = fmaf(x, w.x, facc[i][0]);
      facc[i][1] = fmaf(x, w.y, facc[i][1]);
    }
  }
#pragma unroll
  for (int i = 0; i < 8; ++i) {
    float2 o; o.x = facc[i][0]; o.y = facc[i][1];
    *(float2*)&out[(size_t)(node0 + nt * 8 + i) * OUT_DIM + ct * 2] = o;
  }
}

extern "C" void kernel_launch(void* const* d_in, const int* in_sizes, int n_in,
                              void* d_out, int out_size, void* d_ws, size_t ws_size,
                              hipStream_t stream) {
  const float* emb   = (const float*)d_in[0];
  const float* Ws0   = (const float*)d_in[1];
  const float* bs0   = (const float*)d_in[2];
  const float* Wn0   = (const float*)d_in[3];
  const float* bn0   = (const float*)d_in[4];
  const float* Ws1   = (const float*)d_in[5];
  const float* bs1   = (const float*)d_in[6];
  const float* Wn1   = (const float*)d_in[7];
  const float* bn1   = (const float*)d_in[8];
  const float* Wout  = (const float*)d_in[9];
  const float* bo    = (const float*)d_in[10];
  const int* input_nodes = (const int*)d_in[11];
  const int* nbr0        = (const int*)d_in[12];
  const int* nbr1        = (const int*)d_in[13];
  float* out = (float*)d_out;

  // Workspace layout (floats):
  float* ws    = (float*)d_ws;
  float* H0    = ws;                       // 65536*128   = 8,388,608
  float* Wcat0 = H0 + (size_t)N_DST0 * HDIM;
  float* Wcat1 = Wcat0 + 256 * 128;
  float* WoutT = Wcat1 + 256 * 128;
  float* bias0 = WoutT + 128 * 64;
  float* bias1 = bias0 + 128;

  prep_kernel<<<64, THREADS, 0, stream>>>(Ws0, Wn0, Ws1, Wn1, Wout,
                                          bs0, bn0, bs1, bn1,
                                          Wcat0, Wcat1, WoutT, bias0, bias1);
  layer0_kernel<<<N_DST0 / MTILE, THREADS, 0, stream>>>(emb, input_nodes, nbr0,
                                                        Wcat0, bias0, H0);
  layer1_kernel<<<N_DST1 / MTILE, THREADS, 0, stream>>>(H0, nbr1, Wcat1, bias1,
                                                        WoutT, bo, out);
}

// Round 2
// 754.792 us; speedup vs baseline: 1.0110x; 1.0110x over previous
//
#include <hip/hip_runtime.h>

// GraphSAGE 2-layer inference, fp32, MI355X.
// R2: phase-split index resolution (break nbr->input_nodes->emb pointer chase).
#define NUM_NODES 1000000
#define HDIM      128
#define OUT_DIM   64
#define FANOUT    16
#define N_SRC0    1048576
#define N_DST0    65536
#define N_DST1    4096

#define THREADS   256
#define MTILE     64      // nodes per block

// ---------------- K0: weight prep ----------------
__global__ __launch_bounds__(THREADS) void prep_kernel(
    const float* __restrict__ Ws0, const float* __restrict__ Wn0,
    const float* __restrict__ Ws1, const float* __restrict__ Wn1,
    const float* __restrict__ Wout,
    const float* __restrict__ bs0, const float* __restrict__ bn0,
    const float* __restrict__ bs1, const float* __restrict__ bn1,
    float* __restrict__ Wcat0, float* __restrict__ Wcat1,
    float* __restrict__ WoutT, float* __restrict__ bias0, float* __restrict__ bias1) {
  int tid = blockIdx.x * blockDim.x + threadIdx.x;
  int stride = gridDim.x * blockDim.x;
  for (int i = tid; i < 256 * 128; i += stride) {
    int k = i >> 7, c = i & 127;
    Wcat0[i] = (k < 128) ? Ws0[c * 128 + k] : Wn0[c * 128 + (k - 128)];
    Wcat1[i] = (k < 128) ? Ws1[c * 128 + k] : Wn1[c * 128 + (k - 128)];
  }
  for (int i = tid; i < 128 * 64; i += stride) {
    int c = i >> 6, o = i & 63;
    WoutT[i] = Wout[o * 128 + c];
  }
  for (int i = tid; i < 128; i += stride) {
    bias0[i] = bs0[i] + bn0[i];
    bias1[i] = bs1[i] + bn1[i];
  }
}

// Shared GEMM epilogue macro-free helpers are inlined in each kernel.

// ---------------- K1: layer 0 ----------------
// Phase A: resolve src indices (input_nodes[nbr0[...]]) into the first 17 ints
//          of each node's Xs row (in-place; no extra LDS).
// Phase B: gather emb rows with 17 independent loads per (node,chunk); mean.
// Phase C: C[64][128] = Xs[64][256] @ Wcat0 + bias, ReLU.
__global__ __launch_bounds__(THREADS) void layer0_kernel(
    const float* __restrict__ emb, const int* __restrict__ input_nodes,
    const int* __restrict__ nbr0, const float* __restrict__ Wcat0,
    const float* __restrict__ bias0, float* __restrict__ H0) {
  __shared__ float Xs[MTILE][256];   // 64 KB
  const int tid = threadIdx.x;
  const int node0 = blockIdx.x * MTILE;
  const float4* __restrict__ emb4 = (const float4*)emb;

  // ---- Phase A: index resolution (fully parallel, 2 rounds) ----
  {
    const int base = node0 * FANOUT;
#pragma unroll
    for (int r = 0; r < (MTILE * FANOUT) / THREADS; ++r) {
      const int i = r * THREADS + tid;            // 0..1023
      const int nb = nbr0[base + i];              // coalesced
      ((int*)&Xs[i >> 4][0])[i & 15] = input_nodes[nb];
    }
    if (tid < MTILE) {
      ((int*)&Xs[tid][0])[16] = input_nodes[node0 + tid];
    }
  }
  __syncthreads();

  // ---- Phase B: gather + mean. Thread = (ln: 8 node-groups, ch: float4 chunk) ----
  const int ln = tid >> 5;   // 0..7
  const int ch = tid & 31;
#pragma unroll 1
  for (int g = 0; g < 8; ++g) {
    const int nl = g * 8 + ln;
    const int* I = (const int*)&Xs[nl][0];
    // read ALL indices into registers before overwriting the row (same-wave
    // program order makes this safe: only this 32-lane group touches row nl)
    int4 ia = *(const int4*)&I[0];
    int4 ib = *(const int4*)&I[4];
    int4 ic = *(const int4*)&I[8];
    int4 id = *(const int4*)&I[12];
    int self = I[16];
    float4 v0  = emb4[(size_t)ia.x * 32 + ch];
    float4 v1  = emb4[(size_t)ia.y * 32 + ch];
    float4 v2  = emb4[(size_t)ia.z * 32 + ch];
    float4 v3  = emb4[(size_t)ia.w * 32 + ch];
    float4 v4  = emb4[(size_t)ib.x * 32 + ch];
    float4 v5  = emb4[(size_t)ib.y * 32 + ch];
    float4 v6  = emb4[(size_t)ib.z * 32 + ch];
    float4 v7  = emb4[(size_t)ib.w * 32 + ch];
    float4 v8  = emb4[(size_t)ic.x * 32 + ch];
    float4 v9  = emb4[(size_t)ic.y * 32 + ch];
    float4 v10 = emb4[(size_t)ic.z * 32 + ch];
    float4 v11 = emb4[(size_t)ic.w * 32 + ch];
    float4 v12 = emb4[(size_t)id.x * 32 + ch];
    float4 v13 = emb4[(size_t)id.y * 32 + ch];
    float4 v14 = emb4[(size_t)id.z * 32 + ch];
    float4 v15 = emb4[(size_t)id.w * 32 + ch];
    float4 s   = emb4[(size_t)self * 32 + ch];
    float4 m;
    m.x = (((v0.x+v1.x)+(v2.x+v3.x))+((v4.x+v5.x)+(v6.x+v7.x)))
        + (((v8.x+v9.x)+(v10.x+v11.x))+((v12.x+v13.x)+(v14.x+v15.x)));
    m.y = (((v0.y+v1.y)+(v2.y+v3.y))+((v4.y+v5.y)+(v6.y+v7.y)))
        + (((v8.y+v9.y)+(v10.y+v11.y))+((v12.y+v13.y)+(v14.y+v15.y)));
    m.z = (((v0.z+v1.z)+(v2.z+v3.z))+((v4.z+v5.z)+(v6.z+v7.z)))
        + (((v8.z+v9.z)+(v10.z+v11.z))+((v12.z+v13.z)+(v14.z+v15.z)));
    m.w = (((v0.w+v1.w)+(v2.w+v3.w))+((v4.w+v5.w)+(v6.w+v7.w)))
        + (((v8.w+v9.w)+(v10.w+v11.w))+((v12.w+v13.w)+(v14.w+v15.w)));
    const float inv = 1.0f / (float)FANOUT;
    m.x *= inv; m.y *= inv; m.z *= inv; m.w *= inv;
    *(float4*)&Xs[nl][ch * 4] = s;
    *(float4*)&Xs[nl][128 + ch * 4] = m;
  }
  __syncthreads();

  // ---- Phase C: GEMM + bias + ReLU ----
  const int ct = tid & 31;   // cols ct*4..ct*4+3
  const int nt = tid >> 5;   // nodes nt*8..nt*8+7
  float acc[8][4];
  {
    float4 b = *(const float4*)&bias0[ct * 4];
#pragma unroll
    for (int i = 0; i < 8; ++i) { acc[i][0] = b.x; acc[i][1] = b.y; acc[i][2] = b.z; acc[i][3] = b.w; }
  }
  const float4* __restrict__ W4 = (const float4*)Wcat0;
  for (int k = 0; k < 256; k += 4) {
    float4 wv[4];
#pragma unroll
    for (int d = 0; d < 4; ++d) wv[d] = W4[(size_t)(k + d) * 32 + ct];
#pragma unroll
    for (int i = 0; i < 8; ++i) {
      float4 x = *(const float4*)&Xs[nt * 8 + i][k];
      float xs[4] = {x.x, x.y, x.z, x.w};
#pragma unroll
      for (int d = 0; d < 4; ++d) {
        acc[i][0] = fmaf(xs[d], wv[d].x, acc[i][0]);
        acc[i][1] = fmaf(xs[d], wv[d].y, acc[i][1]);
        acc[i][2] = fmaf(xs[d], wv[d].z, acc[i][2]);
        acc[i][3] = fmaf(xs[d], wv[d].w, acc[i][3]);
      }
    }
  }
#pragma unroll
  for (int i = 0; i < 8; ++i) {
    float4 o;
    o.x = fmaxf(acc[i][0], 0.f); o.y = fmaxf(acc[i][1], 0.f);
    o.z = fmaxf(acc[i][2], 0.f); o.w = fmaxf(acc[i][3], 0.f);
    *(float4*)&H0[(size_t)(node0 + nt * 8 + i) * HDIM + ct * 4] = o;
  }
}

// ---------------- K2: layer 1 + fused output projection ----------------
__global__ __launch_bounds__(THREADS) void layer1_kernel(
    const float* __restrict__ H0, const int* __restrict__ nbr1,
    const float* __restrict__ Wcat1, const float* __restrict__ bias1,
    const float* __restrict__ WoutT, const float* __restrict__ b_out,
    float* __restrict__ out) {
  __shared__ float Xs[MTILE][256];
  const int tid = threadIdx.x;
  const int node0 = blockIdx.x * MTILE;
  const float4* __restrict__ H04 = (const float4*)H0;

  // Phase A: stage nbr1 indices (single-level) into row-leading ints
  {
    const int base = node0 * FANOUT;
#pragma unroll
    for (int r = 0; r < (MTILE * FANOUT) / THREADS; ++r) {
      const int i = r * THREADS + tid;
      ((int*)&Xs[i >> 4][0])[i & 15] = nbr1[base + i];  // coalesced
    }
  }
  __syncthreads();

  const int ln = tid >> 5;
  const int ch = tid & 31;
#pragma unroll 1
  for (int g = 0; g < 8; ++g) {
    const int nl = g * 8 + ln;
    const int* I = (const int*)&Xs[nl][0];
    int4 ia = *(const int4*)&I[0];
    int4 ib = *(const int4*)&I[4];
    int4 ic = *(const int4*)&I[8];
    int4 id = *(const int4*)&I[12];
    const int self = node0 + nl;   // dst node: row nl of H0 slice directly
    float4 v0  = H04[(size_t)ia.x * 32 + ch];
    float4 v1  = H04[(size_t)ia.y * 32 + ch];
    float4 v2  = H04[(size_t)ia.z * 32 + ch];
    float4 v3  = H04[(size_t)ia.w * 32 + ch];
    float4 v4  = H04[(size_t)ib.x * 32 + ch];
    float4 v5  = H04[(size_t)ib.y * 32 + ch];
    float4 v6  = H04[(size_t)ib.z * 32 + ch];
    float4 v7  = H04[(size_t)ib.w * 32 + ch];
    float4 v8  = H04[(size_t)ic.x * 32 + ch];
    float4 v9  = H04[(size_t)ic.y * 32 + ch];
    float4 v10 = H04[(size_t)ic.z * 32 + ch];
    float4 v11 = H04[(size_t)ic.w * 32 + ch];
    float4 v12 = H04[(size_t)id.x * 32 + ch];
    float4 v13 = H04[(size_t)id.y * 32 + ch];
    float4 v14 = H04[(size_t)id.z * 32 + ch];
    float4 v15 = H04[(size_t)id.w * 32 + ch];
    float4 s   = H04[(size_t)self * 32 + ch];
    float4 m;
    m.x = (((v0.x+v1.x)+(v2.x+v3.x))+((v4.x+v5.x)+(v6.x+v7.x)))
        + (((v8.x+v9.x)+(v10.x+v11.x))+((v12.x+v13.x)+(v14.x+v15.x)));
    m.y = (((v0.y+v1.y)+(v2.y+v3.y))+((v4.y+v5.y)+(v6.y+v7.y)))
        + (((v8.y+v9.y)+(v10.y+v11.y))+((v12.y+v13.y)+(v14.y+v15.y)));
    m.z = (((v0.z+v1.z)+(v2.z+v3.z))+((v4.z+v5.z)+(v6.z+v7.z)))
        + (((v8.z+v9.z)+(v10.z+v11.z))+((v12.z+v13.z)+(v14.z+v15.z)));
    m.w = (((v0.w+v1.w)+(v2.w+v3.w))+((v4.w+v5.w)+(v6.w+v7.w)))
        + (((v8.w+v9.w)+(v10.w+v11.w))+((v12.w+v13.w)+(v14.w+v15.w)));
    const float inv = 1.0f / (float)FANOUT;
    m.x *= inv; m.y *= inv; m.z *= inv; m.w *= inv;
    *(float4*)&Xs[nl][ch * 4] = s;
    *(float4*)&Xs[nl][128 + ch * 4] = m;
  }
  __syncthreads();

  const int ct = tid & 31;
  const int nt = tid >> 5;
  float acc[8][4];
  {
    float4 b = *(const float4*)&bias1[ct * 4];
#pragma unroll
    for (int i = 0; i < 8; ++i) { acc[i][0] = b.x; acc[i][1] = b.y; acc[i][2] = b.z; acc[i][3] = b.w; }
  }
  const float4* __restrict__ W4 = (const float4*)Wcat1;
  for (int k = 0; k < 256; k += 4) {
    float4 wv[4];
#pragma unroll
    for (int d = 0; d < 4; ++d) wv[d] = W4[(size_t)(k + d) * 32 + ct];
#pragma unroll
    for (int i = 0; i < 8; ++i) {
      float4 x = *(const float4*)&Xs[nt * 8 + i][k];
      float xs[4] = {x.x, x.y, x.z, x.w};
#pragma unroll
      for (int d = 0; d < 4; ++d) {
        acc[i][0] = fmaf(xs[d], wv[d].x, acc[i][0]);
        acc[i][1] = fmaf(xs[d], wv[d].y, acc[i][1]);
        acc[i][2] = fmaf(xs[d], wv[d].z, acc[i][2]);
        acc[i][3] = fmaf(xs[d], wv[d].w, acc[i][3]);
      }
    }
  }
  __syncthreads();  // done reading Xs; reuse for C1

  float (*C1)[HDIM] = (float(*)[HDIM])Xs;   // [64][128]
#pragma unroll
  for (int i = 0; i < 8; ++i) {
    float4 o; o.x = acc[i][0]; o.y = acc[i][1]; o.z = acc[i][2]; o.w = acc[i][3];
    *(float4*)&C1[nt * 8 + i][ct * 4] = o;
  }
  __syncthreads();

  float facc[8][2];
  {
    float2 b = *(const float2*)&b_out[ct * 2];
#pragma unroll
    for (int i = 0; i < 8; ++i) { facc[i][0] = b.x; facc[i][1] = b.y; }
  }
  const float2* __restrict__ Wo2 = (const float2*)WoutT;
  for (int c = 0; c < 128; ++c) {
    float2 w = Wo2[(size_t)c * 32 + ct];
#pragma unroll
    for (int i = 0; i < 8; ++i) {
      float x = C1[nt * 8 + i][c];
      facc[i][0] = fmaf(x, w.x, facc[i][0]);
      facc[i][1] = fmaf(x, w.y, facc[i][1]);
    }
  }
#pragma unroll
  for (int i = 0; i < 8; ++i) {
    float2 o; o.x = facc[i][0]; o.y = facc[i][1];
    *(float2*)&out[(size_t)(node0 + nt * 8 + i) * OUT_DIM + ct * 2] = o;
  }
}

extern "C" void kernel_launch(void* const* d_in, const int* in_sizes, int n_in,
                              void* d_out, int out_size, void* d_ws, size_t ws_size,
                              hipStream_t stream) {
  const float* emb   = (const float*)d_in[0];
  const float* Ws0   = (const float*)d_in[1];
  const float* bs0   = (const float*)d_in[2];
  const float* Wn0   = (const float*)d_in[3];
  const float* bn0   = (const float*)d_in[4];
  const float* Ws1   = (const float*)d_in[5];
  const float* bs1   = (const float*)d_in[6];
  const float* Wn1   = (const float*)d_in[7];
  const float* bn1   = (const float*)d_in[8];
  const float* Wout  = (const float*)d_in[9];
  const float* bo    = (const float*)d_in[10];
  const int* input_nodes = (const int*)d_in[11];
  const int* nbr0        = (const int*)d_in[12];
  const int* nbr1        = (const int*)d_in[13];
  float* out = (float*)d_out;

  float* ws    = (float*)d_ws;
  float* H0    = ws;
  float* Wcat0 = H0 + (size_t)N_DST0 * HDIM;
  float* Wcat1 = Wcat0 + 256 * 128;
  float* WoutT = Wcat1 + 256 * 128;
  float* bias0 = WoutT + 128 * 64;
  float* bias1 = bias0 + 128;

  prep_kernel<<<64, THREADS, 0, stream>>>(Ws0, Wn0, Ws1, Wn1, Wout,
                                          bs0, bn0, bs1, bn1,
                                          Wcat0, Wcat1, WoutT, bias0, bias1);
  layer0_kernel<<<N_DST0 / MTILE, THREADS, 0, stream>>>(emb, input_nodes, nbr0,
                                                        Wcat0, bias0, H0);
  layer1_kernel<<<N_DST1 / MTILE, THREADS, 0, stream>>>(H0, nbr1, Wcat1, bias1,
                                                        WoutT, bo, out);
}

// Round 3
// 729.819 us; speedup vs baseline: 1.0456x; 1.0342x over previous
//
#include <hip/hip_runtime.h>

// GraphSAGE 2-layer inference, fp32, MI355X.
// R3: dead-row elision — layer0 skips gather+store for H0 rows never read by
// layer1 (~34.5% of 65536; exact, values provably dead).
#define NUM_NODES 1000000
#define HDIM      128
#define OUT_DIM   64
#define FANOUT    16
#define N_SRC0    1048576
#define N_DST0    65536
#define N_DST1    4096

#define THREADS   256
#define MTILE     64      // nodes per block

// ---------------- K0: weight prep ----------------
__global__ __launch_bounds__(THREADS) void prep_kernel(
    const float* __restrict__ Ws0, const float* __restrict__ Wn0,
    const float* __restrict__ Ws1, const float* __restrict__ Wn1,
    const float* __restrict__ Wout,
    const float* __restrict__ bs0, const float* __restrict__ bn0,
    const float* __restrict__ bs1, const float* __restrict__ bn1,
    float* __restrict__ Wcat0, float* __restrict__ Wcat1,
    float* __restrict__ WoutT, float* __restrict__ bias0, float* __restrict__ bias1) {
  int tid = blockIdx.x * blockDim.x + threadIdx.x;
  int stride = gridDim.x * blockDim.x;
  for (int i = tid; i < 256 * 128; i += stride) {
    int k = i >> 7, c = i & 127;
    Wcat0[i] = (k < 128) ? Ws0[c * 128 + k] : Wn0[c * 128 + (k - 128)];
    Wcat1[i] = (k < 128) ? Ws1[c * 128 + k] : Wn1[c * 128 + (k - 128)];
  }
  for (int i = tid; i < 128 * 64; i += stride) {
    int c = i >> 6, o = i & 63;
    WoutT[i] = Wout[o * 128 + c];
  }
  for (int i = tid; i < 128; i += stride) {
    bias0[i] = bs0[i] + bn0[i];
    bias1[i] = bs1[i] + bn1[i];
  }
}

// ---------------- K_mark: build used-mask for H0 rows ----------------
// used[n]=1 iff n appears in nbr1 or n < N_DST1 (layer-1 self rows).
// Benign write races (all write 1). mask pre-zeroed via hipMemsetAsync.
__global__ __launch_bounds__(THREADS) void mark_kernel(
    const int* __restrict__ nbr1, unsigned char* __restrict__ used) {
  int i = blockIdx.x * blockDim.x + threadIdx.x;
  if (i < N_DST1 * FANOUT) used[nbr1[i]] = 1;
  if (i < N_DST1) used[i] = 1;
}

// ---------------- K1: layer 0 ----------------
__global__ __launch_bounds__(THREADS) void layer0_kernel(
    const float* __restrict__ emb, const int* __restrict__ input_nodes,
    const int* __restrict__ nbr0, const float* __restrict__ Wcat0,
    const float* __restrict__ bias0, const unsigned char* __restrict__ used,
    float* __restrict__ H0) {
  __shared__ float Xs[MTILE][256];   // 64 KB
  __shared__ int uflag[MTILE];
  const int tid = threadIdx.x;
  const int node0 = blockIdx.x * MTILE;
  const float4* __restrict__ emb4 = (const float4*)emb;

  if (tid < MTILE) uflag[tid] = (int)used[node0 + tid];
  __syncthreads();

  // ---- Phase A: index resolution (predicated on row liveness) ----
  {
    const int base = node0 * FANOUT;
#pragma unroll
    for (int r = 0; r < (MTILE * FANOUT) / THREADS; ++r) {
      const int i = r * THREADS + tid;            // 0..1023
      const int row = i >> 4;
      if (uflag[row]) {
        const int nb = nbr0[base + i];            // coalesced
        ((int*)&Xs[row][0])[i & 15] = input_nodes[nb];
      }
    }
    if (tid < MTILE && uflag[tid]) {
      ((int*)&Xs[tid][0])[16] = input_nodes[node0 + tid];
    }
  }
  __syncthreads();

  // ---- Phase B: gather + mean (skipped entirely for dead rows) ----
  const int ln = tid >> 5;   // 0..7
  const int ch = tid & 31;
#pragma unroll 1
  for (int g = 0; g < 8; ++g) {
    const int nl = g * 8 + ln;
    if (!uflag[nl]) continue;   // uniform across the 32-lane node-group
    const int* I = (const int*)&Xs[nl][0];
    int4 ia = *(const int4*)&I[0];
    int4 ib = *(const int4*)&I[4];
    int4 ic = *(const int4*)&I[8];
    int4 id = *(const int4*)&I[12];
    int self = I[16];
    float4 v0  = emb4[(size_t)ia.x * 32 + ch];
    float4 v1  = emb4[(size_t)ia.y * 32 + ch];
    float4 v2  = emb4[(size_t)ia.z * 32 + ch];
    float4 v3  = emb4[(size_t)ia.w * 32 + ch];
    float4 v4  = emb4[(size_t)ib.x * 32 + ch];
    float4 v5  = emb4[(size_t)ib.y * 32 + ch];
    float4 v6  = emb4[(size_t)ib.z * 32 + ch];
    float4 v7  = emb4[(size_t)ib.w * 32 + ch];
    float4 v8  = emb4[(size_t)ic.x * 32 + ch];
    float4 v9  = emb4[(size_t)ic.y * 32 + ch];
    float4 v10 = emb4[(size_t)ic.z * 32 + ch];
    float4 v11 = emb4[(size_t)ic.w * 32 + ch];
    float4 v12 = emb4[(size_t)id.x * 32 + ch];
    float4 v13 = emb4[(size_t)id.y * 32 + ch];
    float4 v14 = emb4[(size_t)id.z * 32 + ch];
    float4 v15 = emb4[(size_t)id.w * 32 + ch];
    float4 s   = emb4[(size_t)self * 32 + ch];
    float4 m;
    m.x = (((v0.x+v1.x)+(v2.x+v3.x))+((v4.x+v5.x)+(v6.x+v7.x)))
        + (((v8.x+v9.x)+(v10.x+v11.x))+((v12.x+v13.x)+(v14.x+v15.x)));
    m.y = (((v0.y+v1.y)+(v2.y+v3.y))+((v4.y+v5.y)+(v6.y+v7.y)))
        + (((v8.y+v9.y)+(v10.y+v11.y))+((v12.y+v13.y)+(v14.y+v15.y)));
    m.z = (((v0.z+v1.z)+(v2.z+v3.z))+((v4.z+v5.z)+(v6.z+v7.z)))
        + (((v8.z+v9.z)+(v10.z+v11.z))+((v12.z+v13.z)+(v14.z+v15.z)));
    m.w = (((v0.w+v1.w)+(v2.w+v3.w))+((v4.w+v5.w)+(v6.w+v7.w)))
        + (((v8.w+v9.w)+(v10.w+v11.w))+((v12.w+v13.w)+(v14.w+v15.w)));
    const float inv = 1.0f / (float)FANOUT;
    m.x *= inv; m.y *= inv; m.z *= inv; m.w *= inv;
    *(float4*)&Xs[nl][ch * 4] = s;
    *(float4*)&Xs[nl][128 + ch * 4] = m;
  }
  __syncthreads();

  // ---- Phase C: GEMM + bias + ReLU (stores predicated; dead rows compute
  // finite garbage that is never read) ----
  const int ct = tid & 31;   // cols ct*4..ct*4+3
  const int nt = tid >> 5;   // nodes nt*8..nt*8+7
  float acc[8][4];
  {
    float4 b = *(const float4*)&bias0[ct * 4];
#pragma unroll
    for (int i = 0; i < 8; ++i) { acc[i][0] = b.x; acc[i][1] = b.y; acc[i][2] = b.z; acc[i][3] = b.w; }
  }
  const float4* __restrict__ W4 = (const float4*)Wcat0;
  for (int k = 0; k < 256; k += 4) {
    float4 wv[4];
#pragma unroll
    for (int d = 0; d < 4; ++d) wv[d] = W4[(size_t)(k + d) * 32 + ct];
#pragma unroll
    for (int i = 0; i < 8; ++i) {
      float4 x = *(const float4*)&Xs[nt * 8 + i][k];
      float xs[4] = {x.x, x.y, x.z, x.w};
#pragma unroll
      for (int d = 0; d < 4; ++d) {
        acc[i][0] = fmaf(xs[d], wv[d].x, acc[i][0]);
        acc[i][1] = fmaf(xs[d], wv[d].y, acc[i][1]);
        acc[i][2] = fmaf(xs[d], wv[d].z, acc[i][2]);
        acc[i][3] = fmaf(xs[d], wv[d].w, acc[i][3]);
      }
    }
  }
#pragma unroll
  for (int i = 0; i < 8; ++i) {
    if (!uflag[nt * 8 + i]) continue;
    float4 o;
    o.x = fmaxf(acc[i][0], 0.f); o.y = fmaxf(acc[i][1], 0.f);
    o.z = fmaxf(acc[i][2], 0.f); o.w = fmaxf(acc[i][3], 0.f);
    *(float4*)&H0[(size_t)(node0 + nt * 8 + i) * HDIM + ct * 4] = o;
  }
}

// ---------------- K2: layer 1 + fused output projection ----------------
__global__ __launch_bounds__(THREADS) void layer1_kernel(
    const float* __restrict__ H0, const int* __restrict__ nbr1,
    const float* __restrict__ Wcat1, const float* __restrict__ bias1,
    const float* __restrict__ WoutT, const float* __restrict__ b_out,
    float* __restrict__ out) {
  __shared__ float Xs[MTILE][256];
  const int tid = threadIdx.x;
  const int node0 = blockIdx.x * MTILE;
  const float4* __restrict__ H04 = (const float4*)H0;

  {
    const int base = node0 * FANOUT;
#pragma unroll
    for (int r = 0; r < (MTILE * FANOUT) / THREADS; ++r) {
      const int i = r * THREADS + tid;
      ((int*)&Xs[i >> 4][0])[i & 15] = nbr1[base + i];  // coalesced
    }
  }
  __syncthreads();

  const int ln = tid >> 5;
  const int ch = tid & 31;
#pragma unroll 1
  for (int g = 0; g < 8; ++g) {
    const int nl = g * 8 + ln;
    const int* I = (const int*)&Xs[nl][0];
    int4 ia = *(const int4*)&I[0];
    int4 ib = *(const int4*)&I[4];
    int4 ic = *(const int4*)&I[8];
    int4 id = *(const int4*)&I[12];
    const int self = node0 + nl;
    float4 v0  = H04[(size_t)ia.x * 32 + ch];
    float4 v1  = H04[(size_t)ia.y * 32 + ch];
    float4 v2  = H04[(size_t)ia.z * 32 + ch];
    float4 v3  = H04[(size_t)ia.w * 32 + ch];
    float4 v4  = H04[(size_t)ib.x * 32 + ch];
    float4 v5  = H04[(size_t)ib.y * 32 + ch];
    float4 v6  = H04[(size_t)ib.z * 32 + ch];
    float4 v7  = H04[(size_t)ib.w * 32 + ch];
    float4 v8  = H04[(size_t)ic.x * 32 + ch];
    float4 v9  = H04[(size_t)ic.y * 32 + ch];
    float4 v10 = H04[(size_t)ic.z * 32 + ch];
    float4 v11 = H04[(size_t)ic.w * 32 + ch];
    float4 v12 = H04[(size_t)id.x * 32 + ch];
    float4 v13 = H04[(size_t)id.y * 32 + ch];
    float4 v14 = H04[(size_t)id.z * 32 + ch];
    float4 v15 = H04[(size_t)id.w * 32 + ch];
    float4 s   = H04[(size_t)self * 32 + ch];
    float4 m;
    m.x = (((v0.x+v1.x)+(v2.x+v3.x))+((v4.x+v5.x)+(v6.x+v7.x)))
        + (((v8.x+v9.x)+(v10.x+v11.x))+((v12.x+v13.x)+(v14.x+v15.x)));
    m.y = (((v0.y+v1.y)+(v2.y+v3.y))+((v4.y+v5.y)+(v6.y+v7.y)))
        + (((v8.y+v9.y)+(v10.y+v11.y))+((v12.y+v13.y)+(v14.y+v15.y)));
    m.z = (((v0.z+v1.z)+(v2.z+v3.z))+((v4.z+v5.z)+(v6.z+v7.z)))
        + (((v8.z+v9.z)+(v10.z+v11.z))+((v12.z+v13.z)+(v14.z+v15.z)));
    m.w = (((v0.w+v1.w)+(v2.w+v3.w))+((v4.w+v5.w)+(v6.w+v7.w)))
        + (((v8.w+v9.w)+(v10.w+v11.w))+((v12.w+v13.w)+(v14.w+v15.w)));
    const float inv = 1.0f / (float)FANOUT;
    m.x *= inv; m.y *= inv; m.z *= inv; m.w *= inv;
    *(float4*)&Xs[nl][ch * 4] = s;
    *(float4*)&Xs[nl][128 + ch * 4] = m;
  }
  __syncthreads();

  const int ct = tid & 31;
  const int nt = tid >> 5;
  float acc[8][4];
  {
    float4 b = *(const float4*)&bias1[ct * 4];
#pragma unroll
    for (int i = 0; i < 8; ++i) { acc[i][0] = b.x; acc[i][1] = b.y; acc[i][2] = b.z; acc[i][3] = b.w; }
  }
  const float4* __restrict__ W4 = (const float4*)Wcat1;
  for (int k = 0; k < 256; k += 4) {
    float4 wv[4];
#pragma unroll
    for (int d = 0; d < 4; ++d) wv[d] = W4[(size_t)(k + d) * 32 + ct];
#pragma unroll
    for (int i = 0; i < 8; ++i) {
      float4 x = *(const float4*)&Xs[nt * 8 + i][k];
      float xs[4] = {x.x, x.y, x.z, x.w};
#pragma unroll
      for (int d = 0; d < 4; ++d) {
        acc[i][0] = fmaf(xs[d], wv[d].x, acc[i][0]);
        acc[i][1] = fmaf(xs[d], wv[d].y, acc[i][1]);
        acc[i][2] = fmaf(xs[d], wv[d].z, acc[i][2]);
        acc[i][3] = fmaf(xs[d], wv[d].w, acc[i][3]);
      }
    }
  }
  __syncthreads();  // done reading Xs; reuse for C1

  float (*C1)[HDIM] = (float(*)[HDIM])Xs;   // [64][128]
#pragma unroll
  for (int i = 0; i < 8; ++i) {
    float4 o; o.x = acc[i][0]; o.y = acc[i][1]; o.z = acc[i][2]; o.w = acc[i][3];
    *(float4*)&C1[nt * 8 + i][ct * 4] = o;
  }
  __syncthreads();

  float facc[8][2];
  {
    float2 b = *(const float2*)&b_out[ct * 2];
#pragma unroll
    for (int i = 0; i < 8; ++i) { facc[i][0] = b.x; facc[i][1] = b.y; }
  }
  const float2* __restrict__ Wo2 = (const float2*)WoutT;
  for (int c = 0; c < 128; ++c) {
    float2 w = Wo2[(size_t)c * 32 + ct];
#pragma unroll
    for (int i = 0; i < 8; ++i) {
      float x = C1[nt * 8 + i][c];
      facc[i][0] = fmaf(x, w.x, facc[i][0]);
      facc[i][1] = fmaf(x, w.y, facc[i][1]);
    }
  }
#pragma unroll
  for (int i = 0; i < 8; ++i) {
    float2 o; o.x = facc[i][0]; o.y = facc[i][1];
    *(float2*)&out[(size_t)(node0 + nt * 8 + i) * OUT_DIM + ct * 2] = o;
  }
}

extern "C" void kernel_launch(void* const* d_in, const int* in_sizes, int n_in,
                              void* d_out, int out_size, void* d_ws, size_t ws_size,
                              hipStream_t stream) {
  const float* emb   = (const float*)d_in[0];
  const float* Ws0   = (const float*)d_in[1];
  const float* bs0   = (const float*)d_in[2];
  const float* Wn0   = (const float*)d_in[3];
  const float* bn0   = (const float*)d_in[4];
  const float* Ws1   = (const float*)d_in[5];
  const float* bs1   = (const float*)d_in[6];
  const float* Wn1   = (const float*)d_in[7];
  const float* bn1   = (const float*)d_in[8];
  const float* Wout  = (const float*)d_in[9];
  const float* bo    = (const float*)d_in[10];
  const int* input_nodes = (const int*)d_in[11];
  const int* nbr0        = (const int*)d_in[12];
  const int* nbr1        = (const int*)d_in[13];
  float* out = (float*)d_out;

  float* ws    = (float*)d_ws;
  float* H0    = ws;
  float* Wcat0 = H0 + (size_t)N_DST0 * HDIM;
  float* Wcat1 = Wcat0 + 256 * 128;
  float* WoutT = Wcat1 + 256 * 128;
  float* bias0 = WoutT + 128 * 64;
  float* bias1 = bias0 + 128;
  unsigned char* used = (unsigned char*)(bias1 + 128);  // N_DST0 bytes

  hipMemsetAsync(used, 0, N_DST0, stream);
  mark_kernel<<<(N_DST0 + THREADS - 1) / THREADS, THREADS, 0, stream>>>(nbr1, used);
  prep_kernel<<<64, THREADS, 0, stream>>>(Ws0, Wn0, Ws1, Wn1, Wout,
                                          bs0, bn0, bs1, bn1,
                                          Wcat0, Wcat1, WoutT, bias0, bias1);
  layer0_kernel<<<N_DST0 / MTILE, THREADS, 0, stream>>>(emb, input_nodes, nbr0,
                                                        Wcat0, bias0, used, H0);
  layer1_kernel<<<N_DST1 / MTILE, THREADS, 0, stream>>>(H0, nbr1, Wcat1, bias1,
                                                        WoutT, bo, out);
}

// Round 4
// 710.034 us; speedup vs baseline: 1.0747x; 1.0279x over previous
//
#include <hip/hip_runtime.h>

// GraphSAGE 2-layer inference, fp32, MI355X.
// R4: alive-row compaction (block-uniform skip of staging+gather+GEMM for dead
// H0 rows), MTILE 32 (4 blocks/CU), fused prep+mark, layer1 re-tiled to 16.
#define NUM_NODES 1000000
#define HDIM      128
#define OUT_DIM   64
#define FANOUT    16
#define N_SRC0    1048576
#define N_DST0    65536
#define N_DST1    4096

#define THREADS   256
#define MTILE0    32      // layer0 nodes per block
#define MTILE1    16      // layer1 nodes per block

// ---------------- K0: fused weight prep + used-mask mark ----------------
// used[] pre-zeroed via hipMemsetAsync. Benign 1-writes races.
__global__ __launch_bounds__(THREADS) void prep_mark_kernel(
    const float* __restrict__ Ws0, const float* __restrict__ Wn0,
    const float* __restrict__ Ws1, const float* __restrict__ Wn1,
    const float* __restrict__ Wout,
    const float* __restrict__ bs0, const float* __restrict__ bn0,
    const float* __restrict__ bs1, const float* __restrict__ bn1,
    const int* __restrict__ nbr1,
    float* __restrict__ Wcat0, float* __restrict__ Wcat1,
    float* __restrict__ WoutT, float* __restrict__ bias0, float* __restrict__ bias1,
    unsigned char* __restrict__ used) {
  int tid = blockIdx.x * blockDim.x + threadIdx.x;
  int stride = gridDim.x * blockDim.x;
  // mark phase: grid is exactly 65536 threads
  if (tid < N_DST1 * FANOUT) used[nbr1[tid]] = 1;
  if (tid < N_DST1) used[tid] = 1;
  // prep phase (grid-stride)
  for (int i = tid; i < 256 * 128; i += stride) {
    int k = i >> 7, c = i & 127;
    Wcat0[i] = (k < 128) ? Ws0[c * 128 + k] : Wn0[c * 128 + (k - 128)];
    Wcat1[i] = (k < 128) ? Ws1[c * 128 + k] : Wn1[c * 128 + (k - 128)];
  }
  for (int i = tid; i < 128 * 64; i += stride) {
    int c = i >> 6, o = i & 63;
    WoutT[i] = Wout[o * 128 + c];
  }
  for (int i = tid; i < 128; i += stride) {
    bias0[i] = bs0[i] + bn0[i];
    bias1[i] = bs1[i] + bn1[i];
  }
}

// ---------------- K1: layer 0 with alive-row compaction ----------------
__global__ __launch_bounds__(THREADS, 4) void layer0_kernel(
    const float* __restrict__ emb, const int* __restrict__ input_nodes,
    const int* __restrict__ nbr0, const float* __restrict__ Wcat0,
    const float* __restrict__ bias0, const unsigned char* __restrict__ used,
    float* __restrict__ H0) {
  __shared__ float Xs[MTILE0][256];   // 32 KB; row r = compacted alive slot r
  __shared__ int alive[MTILE0];
  __shared__ int Acnt;
  const int tid = threadIdx.x;
  const int node0 = blockIdx.x * MTILE0;
  const float4* __restrict__ emb4 = (const float4*)emb;

  // ---- compaction: wave 0, lanes 0..31 evaluate liveness; ballot-compact ----
  if (tid < 64) {
    const int lane = tid;   // wave 0
    const int u = (lane < MTILE0) ? (int)used[node0 + lane] : 0;
    const unsigned long long mask = __ballot(u != 0);
    if (u) {
      const int pos = __popcll(mask & ((1ull << lane) - 1ull));
      alive[pos] = lane;
    }
    if (lane == 0) Acnt = __popcll(mask);
  }
  __syncthreads();
  const int A = Acnt;

  // ---- Phase A: stage resolved src indices for alive slots only ----
  {
    const int base = node0 * FANOUT;
#pragma unroll
    for (int r = 0; r < 2; ++r) {
      const int i = r * THREADS + tid;          // 0..511
      if (i < A * FANOUT) {
        const int slot = i >> 4, j = i & 15;
        const int row = alive[slot];
        const int nb = nbr0[base + row * FANOUT + j];
        ((int*)&Xs[slot][0])[j] = input_nodes[nb];
      }
    }
    if (tid < A) {
      ((int*)&Xs[tid][0])[16] = input_nodes[node0 + alive[tid]];
    }
  }
  __syncthreads();

  // ---- Phase B: gather + mean for alive slots (two 8-row batches) ----
  const int ln = tid >> 5;   // 0..7
  const int ch = tid & 31;
#pragma unroll 1
  for (int g = 0; g < MTILE0 / 8; ++g) {
    const int slot = g * 8 + ln;
    if (slot < A) {          // uniform across the 32-lane node-group
      const int* I = (const int*)&Xs[slot][0];
      int4 ia = *(const int4*)&I[0];
      int4 ib = *(const int4*)&I[4];
      int4 ic = *(const int4*)&I[8];
      int4 id = *(const int4*)&I[12];
      int self = I[16];
      // batch 1
      float4 v0 = emb4[(size_t)ia.x * 32 + ch];
      float4 v1 = emb4[(size_t)ia.y * 32 + ch];
      float4 v2 = emb4[(size_t)ia.z * 32 + ch];
      float4 v3 = emb4[(size_t)ia.w * 32 + ch];
      float4 v4 = emb4[(size_t)ib.x * 32 + ch];
      float4 v5 = emb4[(size_t)ib.y * 32 + ch];
      float4 v6 = emb4[(size_t)ib.z * 32 + ch];
      float4 v7 = emb4[(size_t)ib.w * 32 + ch];
      float4 p;
      p.x = ((v0.x+v1.x)+(v2.x+v3.x)) + ((v4.x+v5.x)+(v6.x+v7.x));
      p.y = ((v0.y+v1.y)+(v2.y+v3.y)) + ((v4.y+v5.y)+(v6.y+v7.y));
      p.z = ((v0.z+v1.z)+(v2.z+v3.z)) + ((v4.z+v5.z)+(v6.z+v7.z));
      p.w = ((v0.w+v1.w)+(v2.w+v3.w)) + ((v4.w+v5.w)+(v6.w+v7.w));
      // batch 2
      float4 w0 = emb4[(size_t)ic.x * 32 + ch];
      float4 w1 = emb4[(size_t)ic.y * 32 + ch];
      float4 w2 = emb4[(size_t)ic.z * 32 + ch];
      float4 w3 = emb4[(size_t)ic.w * 32 + ch];
      float4 w4 = emb4[(size_t)id.x * 32 + ch];
      float4 w5 = emb4[(size_t)id.y * 32 + ch];
      float4 w6 = emb4[(size_t)id.z * 32 + ch];
      float4 w7 = emb4[(size_t)id.w * 32 + ch];
      float4 s  = emb4[(size_t)self * 32 + ch];
      float4 q;
      q.x = ((w0.x+w1.x)+(w2.x+w3.x)) + ((w4.x+w5.x)+(w6.x+w7.x));
      q.y = ((w0.y+w1.y)+(w2.y+w3.y)) + ((w4.y+w5.y)+(w6.y+w7.y));
      q.z = ((w0.z+w1.z)+(w2.z+w3.z)) + ((w4.z+w5.z)+(w6.z+w7.z));
      q.w = ((w0.w+w1.w)+(w2.w+w3.w)) + ((w4.w+w5.w)+(w6.w+w7.w));
      const float inv = 1.0f / (float)FANOUT;
      float4 m;
      m.x = (p.x + q.x) * inv; m.y = (p.y + q.y) * inv;
      m.z = (p.z + q.z) * inv; m.w = (p.w + q.w) * inv;
      *(float4*)&Xs[slot][ch * 4] = s;
      *(float4*)&Xs[slot][128 + ch * 4] = m;
    }
  }
  __syncthreads();

  // ---- Phase C: GEMM + bias + ReLU over alive slots ----
  // thread tile: 4 slots (nt) x 4 cols (ct). Skip k-loop when all 4 slots dead
  // (block-uniform per 32-lane group).
  const int ct = tid & 31;
  const int nt = tid >> 5;   // 0..7 -> slots nt*4..nt*4+3
  if (nt * 4 < A) {
    float acc[4][4];
    {
      float4 b = *(const float4*)&bias0[ct * 4];
#pragma unroll
      for (int i = 0; i < 4; ++i) { acc[i][0] = b.x; acc[i][1] = b.y; acc[i][2] = b.z; acc[i][3] = b.w; }
    }
    const float4* __restrict__ W4 = (const float4*)Wcat0;
    for (int k = 0; k < 256; k += 4) {
      float4 wv[4];
#pragma unroll
      for (int d = 0; d < 4; ++d) wv[d] = W4[(size_t)(k + d) * 32 + ct];
#pragma unroll
      for (int i = 0; i < 4; ++i) {
        float4 x = *(const float4*)&Xs[nt * 4 + i][k];
        float xs[4] = {x.x, x.y, x.z, x.w};
#pragma unroll
        for (int d = 0; d < 4; ++d) {
          acc[i][0] = fmaf(xs[d], wv[d].x, acc[i][0]);
          acc[i][1] = fmaf(xs[d], wv[d].y, acc[i][1]);
          acc[i][2] = fmaf(xs[d], wv[d].z, acc[i][2]);
          acc[i][3] = fmaf(xs[d], wv[d].w, acc[i][3]);
        }
      }
    }
#pragma unroll
    for (int i = 0; i < 4; ++i) {
      const int slot = nt * 4 + i;
      if (slot < A) {
        const int row = alive[slot];
        float4 o;
        o.x = fmaxf(acc[i][0], 0.f); o.y = fmaxf(acc[i][1], 0.f);
        o.z = fmaxf(acc[i][2], 0.f); o.w = fmaxf(acc[i][3], 0.f);
        *(float4*)&H0[(size_t)(node0 + row) * HDIM + ct * 4] = o;
      }
    }
  }
}

// ---------------- K2: layer 1 + fused output projection (MTILE1=16) ----------------
__global__ __launch_bounds__(THREADS) void layer1_kernel(
    const float* __restrict__ H0, const int* __restrict__ nbr1,
    const float* __restrict__ Wcat1, const float* __restrict__ bias1,
    const float* __restrict__ WoutT, const float* __restrict__ b_out,
    float* __restrict__ out) {
  __shared__ float Xs[MTILE1][256];   // 16 KB
  const int tid = threadIdx.x;
  const int node0 = blockIdx.x * MTILE1;
  const float4* __restrict__ H04 = (const float4*)H0;

  // Phase A: stage nbr1 indices (256 slots, one per thread)
  {
    const int base = node0 * FANOUT;
    ((int*)&Xs[tid >> 4][0])[tid & 15] = nbr1[base + tid];  // coalesced
  }
  __syncthreads();

  const int ln = tid >> 5;
  const int ch = tid & 31;
#pragma unroll 1
  for (int g = 0; g < MTILE1 / 8; ++g) {
    const int nl = g * 8 + ln;
    const int* I = (const int*)&Xs[nl][0];
    int4 ia = *(const int4*)&I[0];
    int4 ib = *(const int4*)&I[4];
    int4 ic = *(const int4*)&I[8];
    int4 id = *(const int4*)&I[12];
    const int self = node0 + nl;
    float4 v0  = H04[(size_t)ia.x * 32 + ch];
    float4 v1  = H04[(size_t)ia.y * 32 + ch];
    float4 v2  = H04[(size_t)ia.z * 32 + ch];
    float4 v3  = H04[(size_t)ia.w * 32 + ch];
    float4 v4  = H04[(size_t)ib.x * 32 + ch];
    float4 v5  = H04[(size_t)ib.y * 32 + ch];
    float4 v6  = H04[(size_t)ib.z * 32 + ch];
    float4 v7  = H04[(size_t)ib.w * 32 + ch];
    float4 v8  = H04[(size_t)ic.x * 32 + ch];
    float4 v9  = H04[(size_t)ic.y * 32 + ch];
    float4 v10 = H04[(size_t)ic.z * 32 + ch];
    float4 v11 = H04[(size_t)ic.w * 32 + ch];
    float4 v12 = H04[(size_t)id.x * 32 + ch];
    float4 v13 = H04[(size_t)id.y * 32 + ch];
    float4 v14 = H04[(size_t)id.z * 32 + ch];
    float4 v15 = H04[(size_t)id.w * 32 + ch];
    float4 s   = H04[(size_t)self * 32 + ch];
    float4 m;
    m.x = (((v0.x+v1.x)+(v2.x+v3.x))+((v4.x+v5.x)+(v6.x+v7.x)))
        + (((v8.x+v9.x)+(v10.x+v11.x))+((v12.x+v13.x)+(v14.x+v15.x)));
    m.y = (((v0.y+v1.y)+(v2.y+v3.y))+((v4.y+v5.y)+(v6.y+v7.y)))
        + (((v8.y+v9.y)+(v10.y+v11.y))+((v12.y+v13.y)+(v14.y+v15.y)));
    m.z = (((v0.z+v1.z)+(v2.z+v3.z))+((v4.z+v5.z)+(v6.z+v7.z)))
        + (((v8.z+v9.z)+(v10.z+v11.z))+((v12.z+v13.z)+(v14.z+v15.z)));
    m.w = (((v0.w+v1.w)+(v2.w+v3.w))+((v4.w+v5.w)+(v6.w+v7.w)))
        + (((v8.w+v9.w)+(v10.w+v11.w))+((v12.w+v13.w)+(v14.w+v15.w)));
    const float inv = 1.0f / (float)FANOUT;
    m.x *= inv; m.y *= inv; m.z *= inv; m.w *= inv;
    *(float4*)&Xs[nl][ch * 4] = s;
    *(float4*)&Xs[nl][128 + ch * 4] = m;
  }
  __syncthreads();

  // GEMM: 16 rows x 128 cols; thread = 2 rows (nt) x 4 cols (ct)
  const int ct = tid & 31;
  const int nt = tid >> 5;   // 0..7 -> rows nt*2, nt*2+1
  float acc[2][4];
  {
    float4 b = *(const float4*)&bias1[ct * 4];
#pragma unroll
    for (int i = 0; i < 2; ++i) { acc[i][0] = b.x; acc[i][1] = b.y; acc[i][2] = b.z; acc[i][3] = b.w; }
  }
  const float4* __restrict__ W4 = (const float4*)Wcat1;
  for (int k = 0; k < 256; k += 4) {
    float4 wv[4];
#pragma unroll
    for (int d = 0; d < 4; ++d) wv[d] = W4[(size_t)(k + d) * 32 + ct];
#pragma unroll
    for (int i = 0; i < 2; ++i) {
      float4 x = *(const float4*)&Xs[nt * 2 + i][k];
      float xs[4] = {x.x, x.y, x.z, x.w};
#pragma unroll
      for (int d = 0; d < 4; ++d) {
        acc[i][0] = fmaf(xs[d], wv[d].x, acc[i][0]);
        acc[i][1] = fmaf(xs[d], wv[d].y, acc[i][1]);
        acc[i][2] = fmaf(xs[d], wv[d].z, acc[i][2]);
        acc[i][3] = fmaf(xs[d], wv[d].w, acc[i][3]);
      }
    }
  }
  __syncthreads();  // done reading Xs; reuse for C1

  float (*C1)[HDIM] = (float(*)[HDIM])Xs;   // [16][128] = 8 KB
#pragma unroll
  for (int i = 0; i < 2; ++i) {
    float4 o; o.x = acc[i][0]; o.y = acc[i][1]; o.z = acc[i][2]; o.w = acc[i][3];
    *(float4*)&C1[nt * 2 + i][ct * 4] = o;
  }
  __syncthreads();

  // out[16][64] = C1[16][128] @ WoutT[128][64] + b_out; thread = 2 rows x 2 cols
  float facc[2][2];
  {
    float2 b = *(const float2*)&b_out[ct * 2];
#pragma unroll
    for (int i = 0; i < 2; ++i) { facc[i][0] = b.x; facc[i][1] = b.y; }
  }
  const float2* __restrict__ Wo2 = (const float2*)WoutT;
  for (int c = 0; c < 128; ++c) {
    float2 w = Wo2[(size_t)c * 32 + ct];
#pragma unroll
    for (int i = 0; i < 2; ++i) {
      float x = C1[nt * 2 + i][c];
      facc[i][0] = fmaf(x, w.x, facc[i][0]);
      facc[i][1] = fmaf(x, w.y, facc[i][1]);
    }
  }
#pragma unroll
  for (int i = 0; i < 2; ++i) {
    float2 o; o.x = facc[i][0]; o.y = facc[i][1];
    *(float2*)&out[(size_t)(node0 + nt * 2 + i) * OUT_DIM + ct * 2] = o;
  }
}

extern "C" void kernel_launch(void* const* d_in, const int* in_sizes, int n_in,
                              void* d_out, int out_size, void* d_ws, size_t ws_size,
                              hipStream_t stream) {
  const float* emb   = (const float*)d_in[0];
  const float* Ws0   = (const float*)d_in[1];
  const float* bs0   = (const float*)d_in[2];
  const float* Wn0   = (const float*)d_in[3];
  const float* bn0   = (const float*)d_in[4];
  const float* Ws1   = (const float*)d_in[5];
  const float* bs1   = (const float*)d_in[6];
  const float* Wn1   = (const float*)d_in[7];
  const float* bn1   = (const float*)d_in[8];
  const float* Wout  = (const float*)d_in[9];
  const float* bo    = (const float*)d_in[10];
  const int* input_nodes = (const int*)d_in[11];
  const int* nbr0        = (const int*)d_in[12];
  const int* nbr1        = (const int*)d_in[13];
  float* out = (float*)d_out;

  float* ws    = (float*)d_ws;
  float* H0    = ws;
  float* Wcat0 = H0 + (size_t)N_DST0 * HDIM;
  float* Wcat1 = Wcat0 + 256 * 128;
  float* WoutT = Wcat1 + 256 * 128;
  float* bias0 = WoutT + 128 * 64;
  float* bias1 = bias0 + 128;
  unsigned char* used = (unsigned char*)(bias1 + 128);  // N_DST0 bytes

  hipMemsetAsync(used, 0, N_DST0, stream);
  prep_mark_kernel<<<N_DST0 / THREADS, THREADS, 0, stream>>>(
      Ws0, Wn0, Ws1, Wn1, Wout, bs0, bn0, bs1, bn1, nbr1,
      Wcat0, Wcat1, WoutT, bias0, bias1, used);
  layer0_kernel<<<N_DST0 / MTILE0, THREADS, 0, stream>>>(emb, input_nodes, nbr0,
                                                         Wcat0, bias0, used, H0);
  layer1_kernel<<<N_DST1 / MTILE1, THREADS, 0, stream>>>(H0, nbr1, Wcat1, bias1,
                                                         WoutT, bo, out);
}